// Round 1
// baseline (224.874 us; speedup 1.0000x reference)
//
#include <hip/hip_runtime.h>
#include <hip/hip_bf16.h>
#include <cstdint>
#include <cstddef>

#define N_NODES_C 10000
#define N_EDGES_C 320000
#define IN_FEATS 256
#define NUM_HEADS 8
#define OUT_FEATS 64
#define HD 512  // NUM_HEADS*OUT_FEATS

// ---------------- CSR build ----------------

__global__ void zero_int_kernel(int* __restrict__ p, int n) {
    int i = blockIdx.x * 256 + threadIdx.x;
    if (i < n) p[i] = 0;
}

__global__ void count_kernel(const int* __restrict__ dst, int* __restrict__ deg, int E) {
    int i = blockIdx.x * 256 + threadIdx.x;
    if (i < E) atomicAdd(&deg[dst[i]], 1);
}

__global__ __launch_bounds__(256) void scan_kernel(const int* __restrict__ deg,
                                                   int* __restrict__ row_start,
                                                   int* __restrict__ cursor, int N) {
    __shared__ int part[256];
    int t = threadIdx.x;
    int C = (N + 255) / 256;
    int beg = t * C;
    int end = min(beg + C, N);
    int s = 0;
    for (int i = beg; i < end; ++i) s += deg[i];
    part[t] = s;
    __syncthreads();
    if (t == 0) {
        int run = 0;
        for (int i = 0; i < 256; ++i) { int v = part[i]; part[i] = run; run += v; }
        row_start[N] = run;
    }
    __syncthreads();
    int run = part[t];
    for (int i = beg; i < end; ++i) {
        row_start[i] = run;
        cursor[i] = run;
        run += deg[i];
    }
}

__global__ void scatter_kernel(const int* __restrict__ src, const int* __restrict__ dst,
                               int* __restrict__ cursor, int* __restrict__ slot_src, int E) {
    int i = blockIdx.x * 256 + threadIdx.x;
    if (i < E) {
        int p = atomicAdd(&cursor[dst[i]], 1);
        slot_src[p] = src[i];
    }
}

// ---------------- GEMM: ft = feat @ W  (fp32, 64x64 tile) ----------------

__global__ __launch_bounds__(256) void gemm_kernel(const float* __restrict__ A,
                                                   const float* __restrict__ B,
                                                   float* __restrict__ C, int M) {
    const int K = IN_FEATS;  // 256
    const int N = HD;        // 512
    __shared__ float As[16][68];  // transposed: As[k][m]
    __shared__ float Bs[16][68];  // Bs[k][n]
    const int t = threadIdx.x;
    const int tx = t & 15;
    const int ty = t >> 4;
    const int m0 = blockIdx.x * 64;
    const int n0 = blockIdx.y * 64;
    float acc[4][4] = {{0.f, 0.f, 0.f, 0.f}, {0.f, 0.f, 0.f, 0.f},
                       {0.f, 0.f, 0.f, 0.f}, {0.f, 0.f, 0.f, 0.f}};
    const int lr = t >> 2;        // 0..63  (A row within tile)
    const int lc = (t & 3) * 4;   // 0,4,8,12 (A k-col group)

    for (int kk = 0; kk < K; kk += 16) {
        int arow = m0 + lr;
        float4 av = make_float4(0.f, 0.f, 0.f, 0.f);
        if (arow < M) av = *(const float4*)(A + (size_t)arow * K + kk + lc);
        As[lc + 0][lr] = av.x;
        As[lc + 1][lr] = av.y;
        As[lc + 2][lr] = av.z;
        As[lc + 3][lr] = av.w;
        float4 bv = *(const float4*)(B + (size_t)(kk + ty) * N + n0 + tx * 4);
        *(float4*)&Bs[ty][tx * 4] = bv;
        __syncthreads();
#pragma unroll
        for (int k = 0; k < 16; ++k) {
            float4 a4 = *(const float4*)&As[k][ty * 4];
            float4 b4 = *(const float4*)&Bs[k][tx * 4];
            float ar[4] = {a4.x, a4.y, a4.z, a4.w};
            float br[4] = {b4.x, b4.y, b4.z, b4.w};
#pragma unroll
            for (int i = 0; i < 4; ++i)
#pragma unroll
                for (int j = 0; j < 4; ++j) acc[i][j] = fmaf(ar[i], br[j], acc[i][j]);
        }
        __syncthreads();
    }
#pragma unroll
    for (int i = 0; i < 4; ++i) {
        int r = m0 + ty * 4 + i;
        if (r < M) {
            float4 v = make_float4(acc[i][0], acc[i][1], acc[i][2], acc[i][3]);
            *(float4*)(C + (size_t)r * N + n0 + tx * 4) = v;
        }
    }
}

// ---------------- el/er: per-node per-head dot with attn vectors ----------------

__global__ __launch_bounds__(512) void elr_kernel(const float* __restrict__ ft,
                                                  const float* __restrict__ al,
                                                  const float* __restrict__ ar,
                                                  float* __restrict__ el,
                                                  float* __restrict__ er) {
    const int n = blockIdx.x;
    const int t = threadIdx.x;  // t = h*64 + d
    float v = ft[(size_t)n * HD + t];
    float pl = v * al[t];
    float pr = v * ar[t];
#pragma unroll
    for (int off = 32; off > 0; off >>= 1) {
        pl += __shfl_down(pl, off);
        pr += __shfl_down(pr, off);
    }
    if ((t & 63) == 0) {
        int h = t >> 6;
        el[n * NUM_HEADS + h] = pl;
        er[n * NUM_HEADS + h] = pr;
    }
}

// ---------------- per-dst-node softmax + aggregation ----------------

__global__ __launch_bounds__(512) void agg_kernel(
    const float* __restrict__ ft, const float* __restrict__ el,
    const float* __restrict__ er, const float* __restrict__ adj,
    const int* __restrict__ row_start, const int* __restrict__ slot_src,
    const int* __restrict__ idxp, float* __restrict__ out) {
    const int n = blockIdx.x;
    const int t = threadIdx.x;
    const int row = row_start[n];
    const int cnt = row_start[n + 1] - row;
    const int h = t >> 6;  // output head for accumulation mapping (t = h*64+d)
    if (cnt == 0) {
        out[(size_t)n * HD + t] = 0.f;
        return;
    }
    const int idx = idxp[0];
    const int hh = t & 7;   // head for softmax-phase mapping (t = j0*8+hh)
    const int j0 = t >> 3;  // edge slot 0..63
    const float er_hh = er[n * NUM_HEADS + hh];

    __shared__ float red[512];
    __shared__ float m_s[8];
    __shared__ float is_s[8];

    // pass 1: per-head max over incident edges
    float mloc = -1e30f;
    for (int j = j0; j < cnt; j += 64) {
        int s = slot_src[row + j];
        float e = el[s * NUM_HEADS + hh] + er_hh;
        e = (e > 0.f) ? e : 0.2f * e;
        mloc = fmaxf(mloc, e);
    }
    red[t] = mloc;
    __syncthreads();
#pragma unroll
    for (int off = 256; off >= 8; off >>= 1) {
        if (t < off) red[t] = fmaxf(red[t], red[t + off]);
        __syncthreads();
    }
    if (t < 8) m_s[t] = red[t];
    __syncthreads();
    const float m_hh = m_s[hh];

    // pass 2: per-head sum of exp
    float sloc = 0.f;
    for (int j = j0; j < cnt; j += 64) {
        int s = slot_src[row + j];
        float e = el[s * NUM_HEADS + hh] + er_hh;
        e = (e > 0.f) ? e : 0.2f * e;
        sloc += __expf(e - m_hh);
    }
    red[t] = sloc;
    __syncthreads();
#pragma unroll
    for (int off = 256; off >= 8; off >>= 1) {
        if (t < off) red[t] += red[t + off];
        __syncthreads();
    }
    if (t < 8) is_s[t] = 1.0f / red[t];
    __syncthreads();
    const float inv_hh = is_s[hh];

    // pass 3: weights into LDS (chunks of 64 edges), accumulate ft[src]*w
    __shared__ float w_lds[64][8];
    __shared__ int s_lds[64];
    float acc = 0.f;
    const float* adj_base = adj + (n + idx);
    for (int base = 0; base < cnt; base += 64) {
        int j = base + j0;
        if (j < cnt) {
            int s = slot_src[row + j];
            float e = el[s * NUM_HEADS + hh] + er_hh;
            e = (e > 0.f) ? e : 0.2f * e;
            float w = __expf(e - m_hh) * inv_hh * adj_base[(size_t)(s + idx) * N_NODES_C];
            w_lds[j0][hh] = w;
            if (hh == 0) s_lds[j0] = s;
        }
        __syncthreads();
        int c = min(64, cnt - base);
        for (int jj = 0; jj < c; ++jj) {
            acc = fmaf(w_lds[jj][h], ft[(size_t)s_lds[jj] * HD + t], acc);
        }
        __syncthreads();
    }
    out[(size_t)n * HD + t] = acc;
}

// ---------------- launch ----------------

extern "C" void kernel_launch(void* const* d_in, const int* in_sizes, int n_in,
                              void* d_out, int out_size, void* d_ws, size_t ws_size,
                              hipStream_t stream) {
    const float* feat   = (const float*)d_in[0];
    const float* W      = (const float*)d_in[1];
    const float* attn_l = (const float*)d_in[2];
    const float* attn_r = (const float*)d_in[3];
    const float* adj    = (const float*)d_in[4];
    const int*   src    = (const int*)d_in[5];
    const int*   dst    = (const int*)d_in[6];
    const int*   idxp   = (const int*)d_in[7];
    float* out = (float*)d_out;

    const int M = in_sizes[0] / IN_FEATS;  // 10000
    const int E = in_sizes[5];             // 320000

    char* ws = (char*)d_ws;
    size_t off = 0;
    auto alloc = [&](size_t bytes) -> void* {
        off = (off + 255) & ~(size_t)255;
        void* p = ws + off;
        off += bytes;
        return p;
    };
    float* ft        = (float*)alloc((size_t)M * HD * sizeof(float));
    float* el        = (float*)alloc((size_t)M * NUM_HEADS * sizeof(float));
    float* er        = (float*)alloc((size_t)M * NUM_HEADS * sizeof(float));
    int*   deg       = (int*)alloc((size_t)M * sizeof(int));
    int*   row_start = (int*)alloc((size_t)(M + 1) * sizeof(int));
    int*   cursor    = (int*)alloc((size_t)M * sizeof(int));
    int*   slot_src  = (int*)alloc((size_t)E * sizeof(int));

    zero_int_kernel<<<(M + 255) / 256, 256, 0, stream>>>(deg, M);

    dim3 gemm_grid((M + 63) / 64, HD / 64);
    gemm_kernel<<<gemm_grid, 256, 0, stream>>>(feat, W, ft, M);

    count_kernel<<<(E + 255) / 256, 256, 0, stream>>>(dst, deg, E);
    scan_kernel<<<1, 256, 0, stream>>>(deg, row_start, cursor, M);
    scatter_kernel<<<(E + 255) / 256, 256, 0, stream>>>(src, dst, cursor, slot_src, E);

    elr_kernel<<<M, HD, 0, stream>>>(ft, attn_l, attn_r, el, er);

    agg_kernel<<<M, HD, 0, stream>>>(ft, el, er, adj, row_start, slot_src, idxp, out);
}

// Round 2
// 169.662 us; speedup vs baseline: 1.3254x; 1.3254x over previous
//
#include <hip/hip_runtime.h>
#include <hip/hip_bf16.h>
#include <cstdint>
#include <cstddef>

#define N_NODES_C 10000
#define IN_FEATS 256
#define NUM_HEADS 8
#define OUT_FEATS 64
#define HD 512  // NUM_HEADS*OUT_FEATS
#define CH 32   // edges per chunk in agg

// ---------------- CSR build ----------------

__global__ void count_kernel(const int* __restrict__ dst, int* __restrict__ deg, int E) {
    int i = blockIdx.x * 256 + threadIdx.x;
    if (i < E) atomicAdd(&deg[dst[i]], 1);
}

__global__ __launch_bounds__(256) void scan_kernel(const int* __restrict__ deg,
                                                   int* __restrict__ row_start,
                                                   int* __restrict__ cursor, int N) {
    __shared__ int part[256];
    int t = threadIdx.x;
    int C = (N + 255) / 256;
    int beg = t * C;
    int end = min(beg + C, N);
    int s = 0;
    for (int i = beg; i < end; ++i) s += deg[i];
    part[t] = s;
    __syncthreads();
    if (t == 0) {
        int run = 0;
        for (int i = 0; i < 256; ++i) { int v = part[i]; part[i] = run; run += v; }
        row_start[N] = run;
    }
    __syncthreads();
    int run = part[t];
    for (int i = beg; i < end; ++i) {
        row_start[i] = run;
        cursor[i] = run;
        run += deg[i];
    }
}

__global__ void scatter_kernel(const int* __restrict__ src, const int* __restrict__ dst,
                               int* __restrict__ cursor, int* __restrict__ slot_src, int E) {
    int i = blockIdx.x * 256 + threadIdx.x;
    if (i < E) {
        int p = atomicAdd(&cursor[dst[i]], 1);
        slot_src[p] = src[i];
    }
}

// ---------------- GEMM: ft = feat @ W (fp32), fused el/er + bf16 ft ----------------

__device__ inline unsigned pack_bf2(float a, float b) {
    __hip_bfloat162 h2;
    h2.x = __float2bfloat16(a);
    h2.y = __float2bfloat16(b);
    return *(unsigned*)&h2;
}

__global__ __launch_bounds__(256) void gemm_kernel(const float* __restrict__ A,
                                                   const float* __restrict__ B,
                                                   const float* __restrict__ attn_l,
                                                   const float* __restrict__ attn_r,
                                                   __hip_bfloat16* __restrict__ ftb,
                                                   float* __restrict__ el,
                                                   float* __restrict__ er, int M) {
    const int K = IN_FEATS;  // 256
    const int N = HD;        // 512
    __shared__ float As[16][68];  // transposed: As[k][m]
    __shared__ float Bs[16][68];  // Bs[k][n]
    const int t = threadIdx.x;
    const int tx = t & 15;
    const int ty = t >> 4;
    const int m0 = blockIdx.x * 64;
    const int by = blockIdx.y;      // head index; cols [64*by, 64*by+64)
    const int n0 = by * 64;
    float acc[4][4] = {{0.f, 0.f, 0.f, 0.f}, {0.f, 0.f, 0.f, 0.f},
                       {0.f, 0.f, 0.f, 0.f}, {0.f, 0.f, 0.f, 0.f}};
    const int lr = t >> 2;        // 0..63  (A row within tile)
    const int lc = (t & 3) * 4;   // 0,4,8,12 (A k-col group)

    for (int kk = 0; kk < K; kk += 16) {
        int arow = m0 + lr;
        float4 av = make_float4(0.f, 0.f, 0.f, 0.f);
        if (arow < M) av = *(const float4*)(A + (size_t)arow * K + kk + lc);
        As[lc + 0][lr] = av.x;
        As[lc + 1][lr] = av.y;
        As[lc + 2][lr] = av.z;
        As[lc + 3][lr] = av.w;
        float4 bv = *(const float4*)(B + (size_t)(kk + ty) * N + n0 + tx * 4);
        *(float4*)&Bs[ty][tx * 4] = bv;
        __syncthreads();
#pragma unroll
        for (int k = 0; k < 16; ++k) {
            float4 a4 = *(const float4*)&As[k][ty * 4];
            float4 b4 = *(const float4*)&Bs[k][tx * 4];
            float ar[4] = {a4.x, a4.y, a4.z, a4.w};
            float br[4] = {b4.x, b4.y, b4.z, b4.w};
#pragma unroll
            for (int i = 0; i < 4; ++i)
#pragma unroll
                for (int j = 0; j < 4; ++j) acc[i][j] = fmaf(ar[i], br[j], acc[i][j]);
        }
        __syncthreads();
    }

    // epilogue: bf16 ft store + fused el/er (this block covers head `by` fully)
    float4 al4 = *(const float4*)(attn_l + n0 + tx * 4);
    float4 ar4 = *(const float4*)(attn_r + n0 + tx * 4);
#pragma unroll
    for (int i = 0; i < 4; ++i) {
        int r = m0 + ty * 4 + i;
        float pl = acc[i][0] * al4.x + acc[i][1] * al4.y + acc[i][2] * al4.z + acc[i][3] * al4.w;
        float pr = acc[i][0] * ar4.x + acc[i][1] * ar4.y + acc[i][2] * ar4.z + acc[i][3] * ar4.w;
#pragma unroll
        for (int off = 1; off < 16; off <<= 1) {
            pl += __shfl_xor(pl, off, 16);
            pr += __shfl_xor(pr, off, 16);
        }
        if (r < M) {
            if (tx == 0) {
                el[r * NUM_HEADS + by] = pl;
                er[r * NUM_HEADS + by] = pr;
            }
            unsigned p01 = pack_bf2(acc[i][0], acc[i][1]);
            unsigned p23 = pack_bf2(acc[i][2], acc[i][3]);
            *(uint2*)((unsigned short*)ftb + (size_t)r * N + n0 + tx * 4) = make_uint2(p01, p23);
        }
    }
}

// ---------------- fused single-pass softmax + aggregation ----------------
// out[n,h,d] = (sum_e exp(e)*adj*ft[s,h,d]) / (sum_e exp(e))
// No max subtraction needed: |e| <= ~7 so exp is fp32-safe.

__global__ __launch_bounds__(256) void agg_kernel(
    const __hip_bfloat16* __restrict__ ftb, const float* __restrict__ el,
    const float* __restrict__ er, const float* __restrict__ adj,
    const int* __restrict__ row_start, const int* __restrict__ slot_src,
    const int* __restrict__ idxp, float* __restrict__ out) {
    const int n = blockIdx.x;
    const int t = threadIdx.x;
    const int row = row_start[n];
    const int cnt = row_start[n + 1] - row;
    const int h2 = t >> 5;  // head of output elements (2t, 2t+1)
    if (cnt == 0) {
        *(float2*)(out + (size_t)n * HD + 2 * t) = make_float2(0.f, 0.f);
        return;
    }
    const int idx = idxp[0];
    const int hh = t & 7;   // head in edge phase
    const int j0 = t >> 3;  // edge slot within chunk, 0..31
    const float er_hh = er[n * NUM_HEADS + hh];

    __shared__ float w_lds[2][CH][8];
    __shared__ int s_lds[2][CH];
    __shared__ float red[256];

    float ssum = 0.f;
    float2 acc = make_float2(0.f, 0.f);
    int buf = 0;
    for (int base = 0; base < cnt; base += CH) {
        int j = base + j0;
        if (j < cnt) {
            int s = slot_src[row + j];
            float e = el[s * NUM_HEADS + hh] + er_hh;
            e = (e > 0.f) ? e : 0.2f * e;
            float p = __expf(e);
            ssum += p;
            float av = adj[(size_t)(s + idx) * N_NODES_C + (n + idx)];
            w_lds[buf][j0][hh] = p * av;
            if (hh == 0) s_lds[buf][j0] = s;
        }
        __syncthreads();
        int c = min(CH, cnt - base);
        const float* wrow = &w_lds[buf][0][0];
        const int* srow = &s_lds[buf][0];
        for (int jj = 0; jj < c; ++jj) {
            int s = srow[jj];
            float w = wrow[jj * 8 + h2];
            unsigned u = *(const unsigned*)((const unsigned short*)ftb + (size_t)s * HD + 2 * t);
            float fx = __uint_as_float((u & 0xffffu) << 16);
            float fy = __uint_as_float(u & 0xffff0000u);
            acc.x = fmaf(w, fx, acc.x);
            acc.y = fmaf(w, fy, acc.y);
        }
        buf ^= 1;
    }
    // reduce ssum: indices t and t+off share (t&7)=head for off multiples of 8
    red[t] = ssum;
    __syncthreads();
#pragma unroll
    for (int off = 128; off >= 8; off >>= 1) {
        if (t < off) red[t] += red[t + off];
        __syncthreads();
    }
    float inv = 1.0f / red[h2];
    float2 o = make_float2(acc.x * inv, acc.y * inv);
    *(float2*)(out + (size_t)n * HD + 2 * t) = o;
}

// ---------------- launch ----------------

extern "C" void kernel_launch(void* const* d_in, const int* in_sizes, int n_in,
                              void* d_out, int out_size, void* d_ws, size_t ws_size,
                              hipStream_t stream) {
    const float* feat   = (const float*)d_in[0];
    const float* W      = (const float*)d_in[1];
    const float* attn_l = (const float*)d_in[2];
    const float* attn_r = (const float*)d_in[3];
    const float* adj    = (const float*)d_in[4];
    const int*   src    = (const int*)d_in[5];
    const int*   dst    = (const int*)d_in[6];
    const int*   idxp   = (const int*)d_in[7];
    float* out = (float*)d_out;

    const int M = in_sizes[0] / IN_FEATS;  // 10000
    const int E = in_sizes[5];             // 320000

    char* ws = (char*)d_ws;
    size_t off = 0;
    auto alloc = [&](size_t bytes) -> void* {
        off = (off + 255) & ~(size_t)255;
        void* p = ws + off;
        off += bytes;
        return p;
    };
    __hip_bfloat16* ftb = (__hip_bfloat16*)alloc((size_t)M * HD * sizeof(__hip_bfloat16));
    float* el        = (float*)alloc((size_t)M * NUM_HEADS * sizeof(float));
    float* er        = (float*)alloc((size_t)M * NUM_HEADS * sizeof(float));
    int*   deg       = (int*)alloc((size_t)M * sizeof(int));
    int*   row_start = (int*)alloc((size_t)(M + 1) * sizeof(int));
    int*   cursor    = (int*)alloc((size_t)M * sizeof(int));
    int*   slot_src  = (int*)alloc((size_t)E * sizeof(int));

    hipMemsetAsync(deg, 0, (size_t)M * sizeof(int), stream);
    count_kernel<<<(E + 255) / 256, 256, 0, stream>>>(dst, deg, E);
    scan_kernel<<<1, 256, 0, stream>>>(deg, row_start, cursor, M);
    scatter_kernel<<<(E + 255) / 256, 256, 0, stream>>>(src, dst, cursor, slot_src, E);

    dim3 gemm_grid((M + 63) / 64, NUM_HEADS);
    gemm_kernel<<<gemm_grid, 256, 0, stream>>>(feat, W, attn_l, attn_r, ftb, el, er, M);

    agg_kernel<<<M, 256, 0, stream>>>(ftb, el, er, adj, row_start, slot_src, idxp, out);
}

// Round 3
// 154.317 us; speedup vs baseline: 1.4572x; 1.0994x over previous
//
#include <hip/hip_runtime.h>
#include <hip/hip_bf16.h>
#include <cstdint>
#include <cstddef>

#define N_NODES_C 10000
#define IN_FEATS 256
#define NUM_HEADS 8
#define OUT_FEATS 64
#define HD 512   // NUM_HEADS*OUT_FEATS
#define CH 32    // edges per chunk in agg

typedef __attribute__((ext_vector_type(8))) short bf16x8;
typedef __attribute__((ext_vector_type(4))) float f32x4;

__device__ inline unsigned short bf16_bits(float f) {
    unsigned x = __float_as_uint(f);
    x += 0x7fffu + ((x >> 16) & 1u);  // RNE
    return (unsigned short)(x >> 16);
}
__device__ inline float bf16_to_f(unsigned short u) {
    return __uint_as_float(((unsigned)u) << 16);
}

// ---------------- wl/wr = W . attn  -> wlr[k][16] (wl: h 0..7, wr: h 8..15) ----------------

__global__ __launch_bounds__(64) void wlr_kernel(const float* __restrict__ W,
                                                 const float* __restrict__ al,
                                                 const float* __restrict__ ar,
                                                 float* __restrict__ wlr) {
    const int k = blockIdx.x;     // 0..255
    const int l = threadIdx.x;    // 0..63, cols 8l..8l+7, head = l>>3
    float4 w0 = *(const float4*)(W + (size_t)k * HD + 8 * l);
    float4 w1 = *(const float4*)(W + (size_t)k * HD + 8 * l + 4);
    float4 a0 = *(const float4*)(al + 8 * l);
    float4 a1 = *(const float4*)(al + 8 * l + 4);
    float4 b0 = *(const float4*)(ar + 8 * l);
    float4 b1 = *(const float4*)(ar + 8 * l + 4);
    float pl = w0.x * a0.x + w0.y * a0.y + w0.z * a0.z + w0.w * a0.w +
               w1.x * a1.x + w1.y * a1.y + w1.z * a1.z + w1.w * a1.w;
    float pr = w0.x * b0.x + w0.y * b0.y + w0.z * b0.z + w0.w * b0.w +
               w1.x * b1.x + w1.y * b1.y + w1.z * b1.z + w1.w * b1.w;
#pragma unroll
    for (int off = 1; off < 8; off <<= 1) {
        pl += __shfl_xor(pl, off);
        pr += __shfl_xor(pr, off);
    }
    if ((l & 7) == 0) {
        wlr[k * 16 + (l >> 3)] = pl;
        wlr[k * 16 + 8 + (l >> 3)] = pr;
    }
}

// ---------------- Wt[h][d][k] = W[k][h*64+d]  (bf16, per-head transpose) ----------------

__global__ __launch_bounds__(256) void wt_kernel(const float* __restrict__ W,
                                                 unsigned short* __restrict__ Wt) {
    __shared__ float tile[64][65];
    const int b = blockIdx.x;   // 0..31
    const int h = b >> 2;
    const int k0 = (b & 3) * 64;
    const int t = threadIdx.x;
#pragma unroll 4
    for (int it = 0; it < 16; ++it) {
        int r = it * 4 + (t >> 6);
        int c = t & 63;
        tile[r][c] = W[(size_t)(k0 + r) * HD + h * 64 + c];
    }
    __syncthreads();
#pragma unroll 4
    for (int it = 0; it < 16; ++it) {
        int c = it * 4 + (t >> 6);
        int k = t & 63;
        Wt[((size_t)h * 64 + c) * IN_FEATS + k0 + k] = bf16_bits(tile[k][c]);
    }
}

// ---------------- CSR build ----------------

__global__ void count_kernel(const int* __restrict__ dst, int* __restrict__ deg, int E) {
    int i = blockIdx.x * 256 + threadIdx.x;
    if (i < E) atomicAdd(&deg[dst[i]], 1);
}

__global__ __launch_bounds__(1024) void scan_kernel(const int* __restrict__ deg,
                                                    int* __restrict__ row_start,
                                                    int* __restrict__ cursor, int N) {
    __shared__ int wsum[16];
    __shared__ int woff[16];
    const int t = threadIdx.x;
    const int C = (N + 1023) / 1024;
    const int beg = t * C;
    const int end = min(beg + C, N);
    int s = 0;
    for (int i = beg; i < end; ++i) s += deg[i];
    const int lane = t & 63, wv = t >> 6;
    int v = s;
#pragma unroll
    for (int off = 1; off < 64; off <<= 1) {
        int u = __shfl_up(v, off);
        if (lane >= off) v += u;
    }
    if (lane == 63) wsum[wv] = v;
    __syncthreads();
    if (t == 0) {
        int run = 0;
#pragma unroll
        for (int i = 0; i < 16; ++i) { woff[i] = run; run += wsum[i]; }
        row_start[N] = run;
    }
    __syncthreads();
    int run = woff[wv] + v - s;  // exclusive prefix
    for (int i = beg; i < end; ++i) {
        row_start[i] = run;
        cursor[i] = run;
        run += deg[i];
    }
}

__global__ void scatter_kernel(const int* __restrict__ src, const int* __restrict__ dst,
                               int* __restrict__ cursor, int* __restrict__ slot_src, int E) {
    int i = blockIdx.x * 256 + threadIdx.x;
    if (i < E) {
        int p = atomicAdd(&cursor[dst[i]], 1);
        slot_src[p] = src[i];
    }
}

// ---------------- el/er = feat @ wlr  + featb = bf16(feat) ----------------

__global__ __launch_bounds__(256) void elr_kernel(const float* __restrict__ feat,
                                                  const float* __restrict__ wlr,
                                                  unsigned short* __restrict__ featb,
                                                  float* __restrict__ el,
                                                  float* __restrict__ er, int M) {
    __shared__ float wle[256][17];
    const int t = threadIdx.x;
    for (int i = t; i < 256 * 16; i += 256) wle[i >> 4][i & 15] = wlr[i];
    __syncthreads();
    const int lane = t & 63, wv = t >> 6;
    const int n = blockIdx.x * 4 + wv;
    if (n >= M) return;
    const float* frow = feat + (size_t)n * IN_FEATS;
    unsigned short* fbrow = featb + (size_t)n * IN_FEATS;
    float p[16];
#pragma unroll
    for (int h = 0; h < 16; ++h) p[h] = 0.f;
#pragma unroll
    for (int j = 0; j < 4; ++j) {
        int k = lane + 64 * j;
        float fv = frow[k];
        fbrow[k] = bf16_bits(fv);
#pragma unroll
        for (int h = 0; h < 16; ++h) p[h] = fmaf(fv, wle[k][h], p[h]);
    }
    float outv = 0.f;
#pragma unroll
    for (int h = 0; h < 16; ++h) {
        float v = p[h];
#pragma unroll
        for (int off = 32; off; off >>= 1) v += __shfl_xor(v, off);
        outv = (lane == h) ? v : outv;
    }
    if (lane < 8) el[n * NUM_HEADS + lane] = outv;
    else if (lane < 16) er[n * NUM_HEADS + lane - 8] = outv;
}

// ---------------- agg: h[n,h,k] = (sum_j p_j*adj_j*featb[s_j,k]) / sum_j p_j ----------------

__global__ __launch_bounds__(256) void agg_kernel(
    const unsigned short* __restrict__ featb, const float* __restrict__ el,
    const float* __restrict__ er, const float* __restrict__ adj,
    const int* __restrict__ row_start, const int* __restrict__ slot_src,
    const int* __restrict__ idxp, unsigned short* __restrict__ hb) {
    const int n = blockIdx.x;
    const int t = threadIdx.x;  // feat dim
    const int row = row_start[n];
    const int cnt = row_start[n + 1] - row;
    if (cnt == 0) {
#pragma unroll
        for (int h = 0; h < 8; ++h) hb[(size_t)n * 2048 + h * 256 + t] = 0;
        return;
    }
    const int idx = idxp[0];
    const int hh = t & 7;
    const int j0 = t >> 3;  // 0..31
    const float er_hh = er[n * NUM_HEADS + hh];
    const float* adj_col = adj + (size_t)idx * N_NODES_C + (n + idx);

    __shared__ float w_lds[2][CH][8];
    __shared__ int s_lds[2][CH];
    __shared__ float red[256];
    __shared__ float inv_s[8];

    float ssum = 0.f;
    float acc[8] = {0.f, 0.f, 0.f, 0.f, 0.f, 0.f, 0.f, 0.f};
    int buf = 0;
    for (int base = 0; base < cnt; base += CH) {
        int j = base + j0;
        if (j < cnt) {
            int s = slot_src[row + j];
            float e = el[s * NUM_HEADS + hh] + er_hh;
            e = (e > 0.f) ? e : 0.2f * e;
            float p = __expf(e);
            ssum += p;
            w_lds[buf][j0][hh] = p * adj_col[(size_t)s * N_NODES_C];
            if (hh == 0) s_lds[buf][j0] = s;
        }
        __syncthreads();
        int c = min(CH, cnt - base);
#pragma unroll 4
        for (int jj = 0; jj < c; ++jj) {
            int s = s_lds[buf][jj];
            float fv = bf16_to_f(featb[(size_t)s * IN_FEATS + t]);
            float4 w0 = *(const float4*)&w_lds[buf][jj][0];
            float4 w1 = *(const float4*)&w_lds[buf][jj][4];
            acc[0] = fmaf(w0.x, fv, acc[0]);
            acc[1] = fmaf(w0.y, fv, acc[1]);
            acc[2] = fmaf(w0.z, fv, acc[2]);
            acc[3] = fmaf(w0.w, fv, acc[3]);
            acc[4] = fmaf(w1.x, fv, acc[4]);
            acc[5] = fmaf(w1.y, fv, acc[5]);
            acc[6] = fmaf(w1.z, fv, acc[6]);
            acc[7] = fmaf(w1.w, fv, acc[7]);
        }
        buf ^= 1;
    }
    red[t] = ssum;
    __syncthreads();
#pragma unroll
    for (int off = 128; off >= 8; off >>= 1) {
        if (t < off) red[t] += red[t + off];
        __syncthreads();
    }
    if (t < 8) inv_s[t] = 1.f / red[t];
    __syncthreads();
    float4 i0 = *(const float4*)&inv_s[0];
    float4 i1 = *(const float4*)&inv_s[4];
    const float iv[8] = {i0.x, i0.y, i0.z, i0.w, i1.x, i1.y, i1.z, i1.w};
#pragma unroll
    for (int h = 0; h < 8; ++h)
        hb[(size_t)n * 2048 + h * 256 + t] = bf16_bits(acc[h] * iv[h]);
}

// ---------------- out[n, h*64+d] = sum_k hb[n,h,k] * Wt[h,d,k]  (bf16 MFMA) ----------------

__global__ __launch_bounds__(256) void out_gemm_kernel(const short* __restrict__ hb,
                                                       const short* __restrict__ Wt,
                                                       float* __restrict__ out, int M) {
    const int t = threadIdx.x;
    const int lane = t & 63, wv = t >> 6;
    const int by = blockIdx.y;               // head
    const int n0 = blockIdx.x * 64 + wv * 16;
    const int r = lane & 15;
    const int kg = lane >> 4;                // 0..3
    const int arow = min(n0 + r, M - 1);
    const short* aptr = hb + (size_t)arow * 2048 + by * IN_FEATS + kg * 8;
    const short* bptr = Wt + ((size_t)by * 64 + r) * IN_FEATS + kg * 8;
    f32x4 acc[4];
#pragma unroll
    for (int c = 0; c < 4; ++c) acc[c] = (f32x4){0.f, 0.f, 0.f, 0.f};
#pragma unroll
    for (int kk = 0; kk < IN_FEATS; kk += 32) {
        bf16x8 a = *(const bf16x8*)(aptr + kk);
#pragma unroll
        for (int c = 0; c < 4; ++c) {
            bf16x8 b = *(const bf16x8*)(bptr + (size_t)c * 16 * IN_FEATS + kk);
            acc[c] = __builtin_amdgcn_mfma_f32_16x16x32_bf16(a, b, acc[c], 0, 0, 0);
        }
    }
    const int orow0 = n0 + kg * 4;
#pragma unroll
    for (int c = 0; c < 4; ++c) {
#pragma unroll
        for (int i = 0; i < 4; ++i) {
            int rr = orow0 + i;
            if (rr < M) out[(size_t)rr * HD + by * 64 + c * 16 + r] = acc[c][i];
        }
    }
}

// ---------------- launch ----------------

extern "C" void kernel_launch(void* const* d_in, const int* in_sizes, int n_in,
                              void* d_out, int out_size, void* d_ws, size_t ws_size,
                              hipStream_t stream) {
    const float* feat   = (const float*)d_in[0];
    const float* W      = (const float*)d_in[1];
    const float* attn_l = (const float*)d_in[2];
    const float* attn_r = (const float*)d_in[3];
    const float* adj    = (const float*)d_in[4];
    const int*   src    = (const int*)d_in[5];
    const int*   dst    = (const int*)d_in[6];
    const int*   idxp   = (const int*)d_in[7];
    float* out = (float*)d_out;

    const int M = in_sizes[0] / IN_FEATS;  // 10000
    const int E = in_sizes[5];             // 320000

    char* ws = (char*)d_ws;
    size_t off = 0;
    auto alloc = [&](size_t bytes) -> void* {
        off = (off + 255) & ~(size_t)255;
        void* p = ws + off;
        off += bytes;
        return p;
    };
    unsigned short* featb = (unsigned short*)alloc((size_t)M * IN_FEATS * sizeof(short));
    unsigned short* hbuf  = (unsigned short*)alloc((size_t)M * 2048 * sizeof(short));
    unsigned short* Wt    = (unsigned short*)alloc((size_t)HD * IN_FEATS * sizeof(short));
    float* wlr       = (float*)alloc((size_t)IN_FEATS * 16 * sizeof(float));
    float* el        = (float*)alloc((size_t)M * NUM_HEADS * sizeof(float));
    float* er        = (float*)alloc((size_t)M * NUM_HEADS * sizeof(float));
    int*   deg       = (int*)alloc((size_t)M * sizeof(int));
    int*   row_start = (int*)alloc((size_t)(M + 1) * sizeof(int));
    int*   cursor    = (int*)alloc((size_t)M * sizeof(int));
    int*   slot_src  = (int*)alloc((size_t)E * sizeof(int));

    hipMemsetAsync(deg, 0, (size_t)M * sizeof(int), stream);
    wlr_kernel<<<IN_FEATS, 64, 0, stream>>>(W, attn_l, attn_r, wlr);
    wt_kernel<<<32, 256, 0, stream>>>(W, Wt);
    count_kernel<<<(E + 255) / 256, 256, 0, stream>>>(dst, deg, E);
    scan_kernel<<<1, 1024, 0, stream>>>(deg, row_start, cursor, M);
    scatter_kernel<<<(E + 255) / 256, 256, 0, stream>>>(src, dst, cursor, slot_src, E);
    elr_kernel<<<(M + 3) / 4, 256, 0, stream>>>(feat, wlr, featb, el, er, M);
    agg_kernel<<<M, 256, 0, stream>>>(featb, el, er, adj, row_start, slot_src, idxp, hbuf);
    dim3 og((M + 63) / 64, NUM_HEADS);
    out_gemm_kernel<<<og, 256, 0, stream>>>((const short*)hbuf, (const short*)Wt, out, M);
}